// Round 3
// baseline (239.924 us; speedup 1.0000x reference)
//
#include <hip/hip_runtime.h>
#include <math.h>

#define EPS 1e-7f
#define FN_PENALTY 10.0f
#define BLOCK 256

__device__ __forceinline__ float waveReduceSum(float v) {
    #pragma unroll
    for (int off = 32; off > 0; off >>= 1)
        v += __shfl_down(v, off, 64);
    return v;
}

__device__ __forceinline__ float4 validate_fix(float4 b) {
    bool invalid = (b.x > b.z) || (b.y > b.w);
    if (invalid) {
        b.x = fmaxf(b.x, 0.0f);
        b.y = fmaxf(b.y, 0.0f);
        b.z = fmaxf(b.z, 0.0f);
        b.w = fmaxf(b.w, 0.0f);
    }
    b.z = fmaxf(b.z, b.x + 1e-6f);
    b.w = fmaxf(b.w, b.y + 1e-6f);
    return b;
}

__device__ __forceinline__ void accum_row(
    float4 lg, int lbl, float4 pb, float4 tb, float cl, float ct,
    float& s_class, float& s_bbox, float& s_giou, float& s_cut)
{
    // ---- focal class loss ----
    float l0 = lg.x, l1 = lg.y, l2 = lg.z, l3 = lg.w;
    float m = fmaxf(fmaxf(l0, l1), fmaxf(l2, l3));
    float e0 = __expf(l0 - m), e1 = __expf(l1 - m),
          e2 = __expf(l2 - m), e3 = __expf(l3 - m);
    float se = e0 + e1 + e2 + e3;
    lbl &= 3;
    float lsel = (lbl == 0) ? l0 : (lbl == 1) ? l1 : (lbl == 2) ? l2 : l3;
    float esel = (lbl == 0) ? e0 : (lbl == 1) ? e1 : (lbl == 2) ? e2 : e3;
    float ce = __logf(se) + m - lsel;            // lse - lsel
    float pt = esel * __builtin_amdgcn_rcpf(se); // exp(-ce) == e_sel/se, rcp ∥ log
    float om = 1.0f - pt;
    s_class += om * om * ce;                     // ALPHA=1, GAMMA=2

    // ---- bbox L1 ----
    s_bbox += fabsf(pb.x - tb.x) + fabsf(pb.y - tb.y)
            + fabsf(pb.z - tb.z) + fabsf(pb.w - tb.w);

    // ---- GIoU ----
    float4 b1 = validate_fix(pb);
    float4 b2 = validate_fix(tb);
    float area1 = (b1.z - b1.x) * (b1.w - b1.y);
    float area2 = (b2.z - b2.x) * (b2.w - b2.y);
    float ltx = fmaxf(b1.x, b2.x), lty = fmaxf(b1.y, b2.y);
    float rbx = fminf(b1.z, b2.z), rby = fminf(b1.w, b2.w);
    float iw = fmaxf(rbx - ltx, 0.0f), ih = fmaxf(rby - lty, 0.0f);
    float inter = iw * ih;
    float uni = area1 + area2 - inter;
    float iou = __fdividef(inter, uni + EPS);
    float ex1 = fminf(b1.x, b2.x), ey1 = fminf(b1.y, b2.y);
    float ex2 = fmaxf(b1.z, b2.z), ey2 = fmaxf(b1.w, b2.w);
    float ew = fmaxf(ex2 - ex1, 0.0f), eh = fmaxf(ey2 - ey1, 0.0f);
    float enc = ew * eh;
    float giou = iou - __fdividef(enc - uni, enc + EPS);
    s_giou += fmaxf(1.0f - giou, 0.0f);

    // ---- weighted BCE ----
    float bce = fmaxf(cl, 0.0f) - cl * ct + __logf(1.0f + __expf(-fabsf(cl)));
    float w = ((ct == 1.0f) && (cl < 0.0f)) ? FN_PENALTY : 1.0f;  // sigmoid<0.5 <=> logit<0
    s_cut += bce * w;
}

__device__ __forceinline__ void block_reduce_store(
    float s_class, float s_bbox, float s_giou, float s_cut,
    float4* __restrict__ out_slot)
{
    s_class = waveReduceSum(s_class);
    s_bbox  = waveReduceSum(s_bbox);
    s_giou  = waveReduceSum(s_giou);
    s_cut   = waveReduceSum(s_cut);

    __shared__ float red[4][4];
    const int lane = threadIdx.x & 63;
    const int wave = threadIdx.x >> 6;
    if (lane == 0) {
        red[wave][0] = s_class;
        red[wave][1] = s_bbox;
        red[wave][2] = s_giou;
        red[wave][3] = s_cut;
    }
    __syncthreads();
    if (threadIdx.x == 0) {
        float4 r;
        r.x = red[0][0] + red[1][0] + red[2][0] + red[3][0];
        r.y = red[0][1] + red[1][1] + red[2][1] + red[3][1];
        r.z = red[0][2] + red[1][2] + red[2][2] + red[3][2];
        r.w = red[0][3] + red[1][3] + red[2][3] + red[3][3];
        *out_slot = r;
    }
}

// Stage 1: round-0 structure (best measured: 49.2 us), grid-stride, 2 rows per
// iteration, 12 loads issued before dependent compute. A/B variable this
// round: PLAIN loads (no nontemporal hint). Inputs total 199 MB < 256 MB
// Infinity Cache — nt was plausibly blocking L3 retention across bench
// iterations (FETCH_SIZE stuck at ~123 MB every round).
__global__ __launch_bounds__(BLOCK) void loss_reduce(
    const float4* __restrict__ pred_logits,
    const int*    __restrict__ labels,
    const float4* __restrict__ pred_boxes,
    const float4* __restrict__ target_boxes,
    const float*  __restrict__ cut_logits,
    const float*  __restrict__ cut_targets,
    float4* __restrict__ block_out, int n)
{
    float s_class = 0.0f, s_bbox = 0.0f, s_giou = 0.0f, s_cut = 0.0f;
    const int stride  = gridDim.x * BLOCK;
    const int stride2 = stride * 2;
    int i = blockIdx.x * BLOCK + threadIdx.x;

    for (; i + stride < n; i += stride2) {
        const int j = i + stride;
        // issue all 12 loads before any dependent use
        float4 lgA = pred_logits[i];
        float4 lgB = pred_logits[j];
        float4 pbA = pred_boxes[i];
        float4 pbB = pred_boxes[j];
        float4 tbA = target_boxes[i];
        float4 tbB = target_boxes[j];
        int    lbA = labels[i];
        int    lbB = labels[j];
        float  clA = cut_logits[i];
        float  clB = cut_logits[j];
        float  ctA = cut_targets[i];
        float  ctB = cut_targets[j];

        accum_row(lgA, lbA, pbA, tbA, clA, ctA, s_class, s_bbox, s_giou, s_cut);
        accum_row(lgB, lbB, pbB, tbB, clB, ctB, s_class, s_bbox, s_giou, s_cut);
    }
    if (i < n) {
        accum_row(pred_logits[i], labels[i], pred_boxes[i], target_boxes[i],
                  cut_logits[i], cut_targets[i],
                  s_class, s_bbox, s_giou, s_cut);
    }

    block_reduce_store(s_class, s_bbox, s_giou, s_cut, &block_out[blockIdx.x]);
}

// Stage 2 (merged): single block reduces all stage-1 partials, writes outputs.
__global__ __launch_bounds__(BLOCK) void finalize_all(
    const float4* __restrict__ in, int n,
    float* __restrict__ out, float inv_n)
{
    float c = 0.0f, b = 0.0f, g = 0.0f, u = 0.0f;
    for (int i = threadIdx.x; i < n; i += BLOCK) {
        float4 r = in[i];
        c += r.x; b += r.y; g += r.z; u += r.w;
    }
    c = waveReduceSum(c);
    b = waveReduceSum(b);
    g = waveReduceSum(g);
    u = waveReduceSum(u);

    __shared__ float red[4][4];
    const int lane = threadIdx.x & 63;
    const int wave = threadIdx.x >> 6;
    if (lane == 0) {
        red[wave][0] = c;
        red[wave][1] = b;
        red[wave][2] = g;
        red[wave][3] = u;
    }
    __syncthreads();
    if (threadIdx.x == 0) {
        float tc = red[0][0] + red[1][0] + red[2][0] + red[3][0];
        float tb = red[0][1] + red[1][1] + red[2][1] + red[3][1];
        float tg = red[0][2] + red[1][2] + red[2][2] + red[3][2];
        float tu = red[0][3] + red[1][3] + red[2][3] + red[3][3];
        float lc   = fmaxf(tc * inv_n, 0.0f);
        float lb   = fmaxf(tb * inv_n * 0.25f, 0.0f);  // mean over 4N elems
        float lg   = fmaxf(tg * inv_n, 0.0f);
        float lcut = fmaxf(tu * inv_n, 0.0f);
        float total = 1.0f * lc + 5.0f * lb + 2.0f * lg + 3.0f * lcut;
        out[0] = total;
        out[1] = lc;
        out[2] = lb;
        out[3] = lg;
        out[4] = lcut;
    }
}

extern "C" void kernel_launch(void* const* d_in, const int* in_sizes, int n_in,
                              void* d_out, int out_size, void* d_ws, size_t ws_size,
                              hipStream_t stream) {
    const float4* pred_logits  = (const float4*)d_in[0];
    const int*    labels       = (const int*)d_in[1];
    const float4* pred_boxes   = (const float4*)d_in[2];
    const float4* target_boxes = (const float4*)d_in[3];
    const float*  cut_logits   = (const float*)d_in[4];
    const float*  cut_targets  = (const float*)d_in[5];
    float4* ws4 = (float4*)d_ws;
    float*  out = (float*)d_out;
    const int n = in_sizes[1];  // rows

    const int grid1 = 2048;   // 8 blocks/CU, 8 rows/thread (4 iters x 2 rows)
    float4* part1 = ws4;      // grid1 entries

    loss_reduce<<<grid1, BLOCK, 0, stream>>>(pred_logits, labels, pred_boxes,
                                             target_boxes, cut_logits, cut_targets,
                                             part1, n);
    finalize_all<<<1, BLOCK, 0, stream>>>(part1, grid1, out, 1.0f / (float)n);
}

// Round 4
// 213.386 us; speedup vs baseline: 1.1244x; 1.1244x over previous
//
#include <hip/hip_runtime.h>
#include <math.h>

#define EPS 1e-7f
#define FN_PENALTY 10.0f
#define BLOCK 256

typedef float vf4 __attribute__((ext_vector_type(4)));

// Non-temporal 16-B load: global_load_dwordx4 nt — bypasses L1 allocation.
// PROTECTED: A/B'd in round 3 — removing nt costs 1.9x (49.2 -> 92 us) at
// identical FETCH_SIZE. L1 thrash avoidance, not cache-residency.
__device__ __forceinline__ float4 ntload4f(const float4* p) {
    vf4 v = __builtin_nontemporal_load((const vf4*)p);
    float4 r; r.x = v.x; r.y = v.y; r.z = v.z; r.w = v.w;
    return r;
}
__device__ __forceinline__ int ntloadi(const int* p) {
    return __builtin_nontemporal_load(p);
}
__device__ __forceinline__ float ntloadf(const float* p) {
    return __builtin_nontemporal_load(p);
}

__device__ __forceinline__ float waveReduceSum(float v) {
    #pragma unroll
    for (int off = 32; off > 0; off >>= 1)
        v += __shfl_down(v, off, 64);
    return v;
}

__device__ __forceinline__ float4 validate_fix(float4 b) {
    bool invalid = (b.x > b.z) || (b.y > b.w);
    if (invalid) {
        b.x = fmaxf(b.x, 0.0f);
        b.y = fmaxf(b.y, 0.0f);
        b.z = fmaxf(b.z, 0.0f);
        b.w = fmaxf(b.w, 0.0f);
    }
    b.z = fmaxf(b.z, b.x + 1e-6f);
    b.w = fmaxf(b.w, b.y + 1e-6f);
    return b;
}

__device__ __forceinline__ void accum_row(
    float4 lg, int lbl, float4 pb, float4 tb, float cl, float ct,
    float& s_class, float& s_bbox, float& s_giou, float& s_cut)
{
    // ---- focal class loss ----
    float l0 = lg.x, l1 = lg.y, l2 = lg.z, l3 = lg.w;
    float m = fmaxf(fmaxf(l0, l1), fmaxf(l2, l3));
    float e0 = __expf(l0 - m), e1 = __expf(l1 - m),
          e2 = __expf(l2 - m), e3 = __expf(l3 - m);
    float se = e0 + e1 + e2 + e3;
    lbl &= 3;
    float lsel = (lbl == 0) ? l0 : (lbl == 1) ? l1 : (lbl == 2) ? l2 : l3;
    float esel = (lbl == 0) ? e0 : (lbl == 1) ? e1 : (lbl == 2) ? e2 : e3;
    float ce = __logf(se) + m - lsel;            // lse - lsel
    float pt = esel * __builtin_amdgcn_rcpf(se); // exp(-ce) == e_sel/se, rcp ∥ log
    float om = 1.0f - pt;
    s_class += om * om * ce;                     // ALPHA=1, GAMMA=2

    // ---- bbox L1 ----
    s_bbox += fabsf(pb.x - tb.x) + fabsf(pb.y - tb.y)
            + fabsf(pb.z - tb.z) + fabsf(pb.w - tb.w);

    // ---- GIoU ----
    float4 b1 = validate_fix(pb);
    float4 b2 = validate_fix(tb);
    float area1 = (b1.z - b1.x) * (b1.w - b1.y);
    float area2 = (b2.z - b2.x) * (b2.w - b2.y);
    float ltx = fmaxf(b1.x, b2.x), lty = fmaxf(b1.y, b2.y);
    float rbx = fminf(b1.z, b2.z), rby = fminf(b1.w, b2.w);
    float iw = fmaxf(rbx - ltx, 0.0f), ih = fmaxf(rby - lty, 0.0f);
    float inter = iw * ih;
    float uni = area1 + area2 - inter;
    float iou = __fdividef(inter, uni + EPS);
    float ex1 = fminf(b1.x, b2.x), ey1 = fminf(b1.y, b2.y);
    float ex2 = fmaxf(b1.z, b2.z), ey2 = fmaxf(b1.w, b2.w);
    float ew = fmaxf(ex2 - ex1, 0.0f), eh = fmaxf(ey2 - ey1, 0.0f);
    float enc = ew * eh;
    float giou = iou - __fdividef(enc - uni, enc + EPS);
    s_giou += fmaxf(1.0f - giou, 0.0f);

    // ---- weighted BCE ----
    float bce = fmaxf(cl, 0.0f) - cl * ct + __logf(1.0f + __expf(-fabsf(cl)));
    float w = ((ct == 1.0f) && (cl < 0.0f)) ? FN_PENALTY : 1.0f;  // sigmoid<0.5 <=> logit<0
    s_cut += bce * w;
}

__device__ __forceinline__ void block_reduce_store(
    float s_class, float s_bbox, float s_giou, float s_cut,
    float4* __restrict__ out_slot)
{
    s_class = waveReduceSum(s_class);
    s_bbox  = waveReduceSum(s_bbox);
    s_giou  = waveReduceSum(s_giou);
    s_cut   = waveReduceSum(s_cut);

    __shared__ float red[4][4];
    const int lane = threadIdx.x & 63;
    const int wave = threadIdx.x >> 6;
    if (lane == 0) {
        red[wave][0] = s_class;
        red[wave][1] = s_bbox;
        red[wave][2] = s_giou;
        red[wave][3] = s_cut;
    }
    __syncthreads();
    if (threadIdx.x == 0) {
        float4 r;
        r.x = red[0][0] + red[1][0] + red[2][0] + red[3][0];
        r.y = red[0][1] + red[1][1] + red[2][1] + red[3][1];
        r.z = red[0][2] + red[1][2] + red[2][2] + red[3][2];
        r.w = red[0][3] + red[1][3] + red[2][3] + red[3][3];
        *out_slot = r;
    }
}

// Stage 1: round-0 structure (best measured: 49.2 us) — grid-stride,
// lane-consecutive addressing, 2 rows per iteration, all 12 loads nt and
// issued before dependent compute. Single variable this round: grid 2048 ->
// 4096 (16 blocks/CU queued) to fix the no-refill residency drain that
// showed as OccupancyPercent ~52% with exactly 8 blocks/CU.
__global__ __launch_bounds__(BLOCK) void loss_reduce(
    const float4* __restrict__ pred_logits,
    const int*    __restrict__ labels,
    const float4* __restrict__ pred_boxes,
    const float4* __restrict__ target_boxes,
    const float*  __restrict__ cut_logits,
    const float*  __restrict__ cut_targets,
    float4* __restrict__ block_out, int n)
{
    float s_class = 0.0f, s_bbox = 0.0f, s_giou = 0.0f, s_cut = 0.0f;
    const int stride  = gridDim.x * BLOCK;
    const int stride2 = stride * 2;
    int i = blockIdx.x * BLOCK + threadIdx.x;

    for (; i + stride < n; i += stride2) {
        const int j = i + stride;
        // issue all 12 loads (nt) before any dependent use
        float4 lgA = ntload4f(&pred_logits[i]);
        float4 lgB = ntload4f(&pred_logits[j]);
        float4 pbA = ntload4f(&pred_boxes[i]);
        float4 pbB = ntload4f(&pred_boxes[j]);
        float4 tbA = ntload4f(&target_boxes[i]);
        float4 tbB = ntload4f(&target_boxes[j]);
        int    lbA = ntloadi(&labels[i]);
        int    lbB = ntloadi(&labels[j]);
        float  clA = ntloadf(&cut_logits[i]);
        float  clB = ntloadf(&cut_logits[j]);
        float  ctA = ntloadf(&cut_targets[i]);
        float  ctB = ntloadf(&cut_targets[j]);

        accum_row(lgA, lbA, pbA, tbA, clA, ctA, s_class, s_bbox, s_giou, s_cut);
        accum_row(lgB, lbB, pbB, tbB, clB, ctB, s_class, s_bbox, s_giou, s_cut);
    }
    if (i < n) {
        accum_row(ntload4f(&pred_logits[i]), ntloadi(&labels[i]),
                  ntload4f(&pred_boxes[i]), ntload4f(&target_boxes[i]),
                  ntloadf(&cut_logits[i]), ntloadf(&cut_targets[i]),
                  s_class, s_bbox, s_giou, s_cut);
    }

    block_reduce_store(s_class, s_bbox, s_giou, s_cut, &block_out[blockIdx.x]);
}

// Stage 2 (merged): single block reduces all stage-1 partials, writes outputs.
__global__ __launch_bounds__(BLOCK) void finalize_all(
    const float4* __restrict__ in, int n,
    float* __restrict__ out, float inv_n)
{
    float c = 0.0f, b = 0.0f, g = 0.0f, u = 0.0f;
    for (int i = threadIdx.x; i < n; i += BLOCK) {
        float4 r = in[i];
        c += r.x; b += r.y; g += r.z; u += r.w;
    }
    c = waveReduceSum(c);
    b = waveReduceSum(b);
    g = waveReduceSum(g);
    u = waveReduceSum(u);

    __shared__ float red[4][4];
    const int lane = threadIdx.x & 63;
    const int wave = threadIdx.x >> 6;
    if (lane == 0) {
        red[wave][0] = c;
        red[wave][1] = b;
        red[wave][2] = g;
        red[wave][3] = u;
    }
    __syncthreads();
    if (threadIdx.x == 0) {
        float tc = red[0][0] + red[1][0] + red[2][0] + red[3][0];
        float tb = red[0][1] + red[1][1] + red[2][1] + red[3][1];
        float tg = red[0][2] + red[1][2] + red[2][2] + red[3][2];
        float tu = red[0][3] + red[1][3] + red[2][3] + red[3][3];
        float lc   = fmaxf(tc * inv_n, 0.0f);
        float lb   = fmaxf(tb * inv_n * 0.25f, 0.0f);  // mean over 4N elems
        float lg   = fmaxf(tg * inv_n, 0.0f);
        float lcut = fmaxf(tu * inv_n, 0.0f);
        float total = 1.0f * lc + 5.0f * lb + 2.0f * lg + 3.0f * lcut;
        out[0] = total;
        out[1] = lc;
        out[2] = lb;
        out[3] = lg;
        out[4] = lcut;
    }
}

extern "C" void kernel_launch(void* const* d_in, const int* in_sizes, int n_in,
                              void* d_out, int out_size, void* d_ws, size_t ws_size,
                              hipStream_t stream) {
    const float4* pred_logits  = (const float4*)d_in[0];
    const int*    labels       = (const int*)d_in[1];
    const float4* pred_boxes   = (const float4*)d_in[2];
    const float4* target_boxes = (const float4*)d_in[3];
    const float*  cut_logits   = (const float*)d_in[4];
    const float*  cut_targets  = (const float*)d_in[5];
    float4* ws4 = (float4*)d_ws;
    float*  out = (float*)d_out;
    const int n = in_sizes[1];  // rows

    const int grid1 = 4096;   // 16 blocks/CU queued; 4 rows/thread (2 iters x 2 rows)
    float4* part1 = ws4;      // grid1 entries

    loss_reduce<<<grid1, BLOCK, 0, stream>>>(pred_logits, labels, pred_boxes,
                                             target_boxes, cut_logits, cut_targets,
                                             part1, n);
    finalize_all<<<1, BLOCK, 0, stream>>>(part1, grid1, out, 1.0f / (float)n);
}

// Round 5
// 213.073 us; speedup vs baseline: 1.1260x; 1.0015x over previous
//
#include <hip/hip_runtime.h>
#include <math.h>

#define EPS 1e-7f
#define FN_PENALTY 10.0f
#define BLOCK 256
#define FBLOCK 1024   // finalize block: 4096 partials / 1024 = 4 loads/thread

typedef float vf4 __attribute__((ext_vector_type(4)));

// Non-temporal 16-B load: global_load_dwordx4 nt — bypasses L1 allocation.
// PROTECTED: A/B'd in round 3 — removing nt costs 1.9x (49.2 -> 92 us) at
// identical FETCH_SIZE. L1 thrash avoidance, not cache-residency.
__device__ __forceinline__ float4 ntload4f(const float4* p) {
    vf4 v = __builtin_nontemporal_load((const vf4*)p);
    float4 r; r.x = v.x; r.y = v.y; r.z = v.z; r.w = v.w;
    return r;
}
__device__ __forceinline__ int ntloadi(const int* p) {
    return __builtin_nontemporal_load(p);
}
__device__ __forceinline__ float ntloadf(const float* p) {
    return __builtin_nontemporal_load(p);
}

__device__ __forceinline__ float waveReduceSum(float v) {
    #pragma unroll
    for (int off = 32; off > 0; off >>= 1)
        v += __shfl_down(v, off, 64);
    return v;
}

__device__ __forceinline__ float4 validate_fix(float4 b) {
    bool invalid = (b.x > b.z) || (b.y > b.w);
    if (invalid) {
        b.x = fmaxf(b.x, 0.0f);
        b.y = fmaxf(b.y, 0.0f);
        b.z = fmaxf(b.z, 0.0f);
        b.w = fmaxf(b.w, 0.0f);
    }
    b.z = fmaxf(b.z, b.x + 1e-6f);
    b.w = fmaxf(b.w, b.y + 1e-6f);
    return b;
}

__device__ __forceinline__ void accum_row(
    float4 lg, int lbl, float4 pb, float4 tb, float cl, float ct,
    float& s_class, float& s_bbox, float& s_giou, float& s_cut)
{
    // ---- focal class loss ----
    float l0 = lg.x, l1 = lg.y, l2 = lg.z, l3 = lg.w;
    float m = fmaxf(fmaxf(l0, l1), fmaxf(l2, l3));
    float e0 = __expf(l0 - m), e1 = __expf(l1 - m),
          e2 = __expf(l2 - m), e3 = __expf(l3 - m);
    float se = e0 + e1 + e2 + e3;
    lbl &= 3;
    float lsel = (lbl == 0) ? l0 : (lbl == 1) ? l1 : (lbl == 2) ? l2 : l3;
    float esel = (lbl == 0) ? e0 : (lbl == 1) ? e1 : (lbl == 2) ? e2 : e3;
    float ce = __logf(se) + m - lsel;            // lse - lsel
    float pt = esel * __builtin_amdgcn_rcpf(se); // exp(-ce) == e_sel/se, rcp ∥ log
    float om = 1.0f - pt;
    s_class += om * om * ce;                     // ALPHA=1, GAMMA=2

    // ---- bbox L1 ----
    s_bbox += fabsf(pb.x - tb.x) + fabsf(pb.y - tb.y)
            + fabsf(pb.z - tb.z) + fabsf(pb.w - tb.w);

    // ---- GIoU ----
    float4 b1 = validate_fix(pb);
    float4 b2 = validate_fix(tb);
    float area1 = (b1.z - b1.x) * (b1.w - b1.y);
    float area2 = (b2.z - b2.x) * (b2.w - b2.y);
    float ltx = fmaxf(b1.x, b2.x), lty = fmaxf(b1.y, b2.y);
    float rbx = fminf(b1.z, b2.z), rby = fminf(b1.w, b2.w);
    float iw = fmaxf(rbx - ltx, 0.0f), ih = fmaxf(rby - lty, 0.0f);
    float inter = iw * ih;
    float uni = area1 + area2 - inter;
    float iou = __fdividef(inter, uni + EPS);
    float ex1 = fminf(b1.x, b2.x), ey1 = fminf(b1.y, b2.y);
    float ex2 = fmaxf(b1.z, b2.z), ey2 = fmaxf(b1.w, b2.w);
    float ew = fmaxf(ex2 - ex1, 0.0f), eh = fmaxf(ey2 - ey1, 0.0f);
    float enc = ew * eh;
    float giou = iou - __fdividef(enc - uni, enc + EPS);
    s_giou += fmaxf(1.0f - giou, 0.0f);

    // ---- weighted BCE ----
    float bce = fmaxf(cl, 0.0f) - cl * ct + __logf(1.0f + __expf(-fabsf(cl)));
    float w = ((ct == 1.0f) && (cl < 0.0f)) ? FN_PENALTY : 1.0f;  // sigmoid<0.5 <=> logit<0
    s_cut += bce * w;
}

__device__ __forceinline__ void block_reduce_store(
    float s_class, float s_bbox, float s_giou, float s_cut,
    float4* __restrict__ out_slot)
{
    s_class = waveReduceSum(s_class);
    s_bbox  = waveReduceSum(s_bbox);
    s_giou  = waveReduceSum(s_giou);
    s_cut   = waveReduceSum(s_cut);

    __shared__ float red[4][4];
    const int lane = threadIdx.x & 63;
    const int wave = threadIdx.x >> 6;
    if (lane == 0) {
        red[wave][0] = s_class;
        red[wave][1] = s_bbox;
        red[wave][2] = s_giou;
        red[wave][3] = s_cut;
    }
    __syncthreads();
    if (threadIdx.x == 0) {
        float4 r;
        r.x = red[0][0] + red[1][0] + red[2][0] + red[3][0];
        r.y = red[0][1] + red[1][1] + red[2][1] + red[3][1];
        r.z = red[0][2] + red[1][2] + red[2][2] + red[3][2];
        r.w = red[0][3] + red[1][3] + red[2][3] + red[3][3];
        *out_slot = r;
    }
}

// Stage 1: FROZEN at the measured optimum (49.2 us): grid-stride 4096 blocks,
// lane-consecutive addressing, 2 rows/iter, all 12 loads nt issued before
// dependent compute. Structural ceiling: 122.9 MB/pass HBM (L3-capacity
// misses, scattered granules) at ~2.5 TB/s ~= 49 us; VALU ~10%/SIMD, MLP
// abundant (r1/r2 nulls), occupancy lever null (r4).
__global__ __launch_bounds__(BLOCK) void loss_reduce(
    const float4* __restrict__ pred_logits,
    const int*    __restrict__ labels,
    const float4* __restrict__ pred_boxes,
    const float4* __restrict__ target_boxes,
    const float*  __restrict__ cut_logits,
    const float*  __restrict__ cut_targets,
    float4* __restrict__ block_out, int n)
{
    float s_class = 0.0f, s_bbox = 0.0f, s_giou = 0.0f, s_cut = 0.0f;
    const int stride  = gridDim.x * BLOCK;
    const int stride2 = stride * 2;
    int i = blockIdx.x * BLOCK + threadIdx.x;

    for (; i + stride < n; i += stride2) {
        const int j = i + stride;
        // issue all 12 loads (nt) before any dependent use
        float4 lgA = ntload4f(&pred_logits[i]);
        float4 lgB = ntload4f(&pred_logits[j]);
        float4 pbA = ntload4f(&pred_boxes[i]);
        float4 pbB = ntload4f(&pred_boxes[j]);
        float4 tbA = ntload4f(&target_boxes[i]);
        float4 tbB = ntload4f(&target_boxes[j]);
        int    lbA = ntloadi(&labels[i]);
        int    lbB = ntloadi(&labels[j]);
        float  clA = ntloadf(&cut_logits[i]);
        float  clB = ntloadf(&cut_logits[j]);
        float  ctA = ntloadf(&cut_targets[i]);
        float  ctB = ntloadf(&cut_targets[j]);

        accum_row(lgA, lbA, pbA, tbA, clA, ctA, s_class, s_bbox, s_giou, s_cut);
        accum_row(lgB, lbB, pbB, tbB, clB, ctB, s_class, s_bbox, s_giou, s_cut);
    }
    if (i < n) {
        accum_row(ntload4f(&pred_logits[i]), ntloadi(&labels[i]),
                  ntload4f(&pred_boxes[i]), ntload4f(&target_boxes[i]),
                  ntloadf(&cut_logits[i]), ntloadf(&cut_targets[i]),
                  s_class, s_bbox, s_giou, s_cut);
    }

    block_reduce_store(s_class, s_bbox, s_giou, s_cut, &block_out[blockIdx.x]);
}

// Stage 2: THIS round's single variable. Old version: 256 threads x 16
// latency-chained iterations over 64 KB of partials scattered across 8 XCDs'
// L2s (~700 cy/hop) ~= 4.1 us. New: 1024 threads, 4 independent loads each
// (guarded, unrolled), 16-wave LDS reduce — ~2 latency rounds ~= 1.5 us.
__global__ __launch_bounds__(FBLOCK) void finalize_all(
    const float4* __restrict__ in, int n,
    float* __restrict__ out, float inv_n)
{
    float c = 0.0f, b = 0.0f, g = 0.0f, u = 0.0f;
    int i = threadIdx.x;
    #pragma unroll 4
    for (int k = 0; k < 4; ++k) {
        if (i < n) {
            float4 r = in[i];
            c += r.x; b += r.y; g += r.z; u += r.w;
        }
        i += FBLOCK;
    }
    for (; i < n; i += FBLOCK) {   // safety: n > 4*FBLOCK
        float4 r = in[i];
        c += r.x; b += r.y; g += r.z; u += r.w;
    }

    c = waveReduceSum(c);
    b = waveReduceSum(b);
    g = waveReduceSum(g);
    u = waveReduceSum(u);

    __shared__ float red[16][4];
    const int lane = threadIdx.x & 63;
    const int wave = threadIdx.x >> 6;
    if (lane == 0) {
        red[wave][0] = c;
        red[wave][1] = b;
        red[wave][2] = g;
        red[wave][3] = u;
    }
    __syncthreads();
    if (threadIdx.x < 16) {
        // 16 lanes each own one component-slice: lane t sums red[t][*]? No —
        // simpler: lane t in [0,16) reduces component (t&3) over rows via
        // strided gather would diverge; do it serially on thread 0 instead
        // (16x4 adds, trivial vs load latency).
    }
    if (threadIdx.x == 0) {
        float tc = 0.0f, tb = 0.0f, tg = 0.0f, tu = 0.0f;
        #pragma unroll
        for (int wv = 0; wv < 16; ++wv) {
            tc += red[wv][0]; tb += red[wv][1];
            tg += red[wv][2]; tu += red[wv][3];
        }
        float lc   = fmaxf(tc * inv_n, 0.0f);
        float lb   = fmaxf(tb * inv_n * 0.25f, 0.0f);  // mean over 4N elems
        float lg   = fmaxf(tg * inv_n, 0.0f);
        float lcut = fmaxf(tu * inv_n, 0.0f);
        float total = 1.0f * lc + 5.0f * lb + 2.0f * lg + 3.0f * lcut;
        out[0] = total;
        out[1] = lc;
        out[2] = lb;
        out[3] = lg;
        out[4] = lcut;
    }
}

extern "C" void kernel_launch(void* const* d_in, const int* in_sizes, int n_in,
                              void* d_out, int out_size, void* d_ws, size_t ws_size,
                              hipStream_t stream) {
    const float4* pred_logits  = (const float4*)d_in[0];
    const int*    labels       = (const int*)d_in[1];
    const float4* pred_boxes   = (const float4*)d_in[2];
    const float4* target_boxes = (const float4*)d_in[3];
    const float*  cut_logits   = (const float*)d_in[4];
    const float*  cut_targets  = (const float*)d_in[5];
    float4* ws4 = (float4*)d_ws;
    float*  out = (float*)d_out;
    const int n = in_sizes[1];  // rows

    const int grid1 = 4096;   // 16 blocks/CU queued; 4 rows/thread (2 iters x 2 rows)
    float4* part1 = ws4;      // grid1 entries

    loss_reduce<<<grid1, BLOCK, 0, stream>>>(pred_logits, labels, pred_boxes,
                                             target_boxes, cut_logits, cut_targets,
                                             part1, n);
    finalize_all<<<1, FBLOCK, 0, stream>>>(part1, grid1, out, 1.0f / (float)n);
}